// Round 8
// baseline (298.247 us; speedup 1.0000x reference)
//
#include <hip/hip_runtime.h>
#include <stdint.h>

#define M_TOT 8192
#define N_TOT 4096
#define K_TOT 4096
#define NTILE 64   // K-tiles of BK=64

typedef __attribute__((ext_vector_type(8))) short bf16x8;
typedef __attribute__((ext_vector_type(4))) float f32x4;
typedef __attribute__((ext_vector_type(2))) unsigned short u16x2;
typedef __attribute__((ext_vector_type(4))) unsigned short u16x4;

typedef const __attribute__((address_space(1))) void* gas1;
typedef __attribute__((address_space(3))) void* las3;

__device__ __forceinline__ unsigned short bf16_rne(float f) {
    union { float f; unsigned int u; } v; v.f = f;
    unsigned int u = v.u;
    return (unsigned short)((u + 0x7FFFu + ((u >> 16) & 1u)) >> 16);
}

// Exact collapse of the reference FP4(E2M1) quant-dequant on a = |w|/scale.
__device__ __forceinline__ float fp4_qdq(float wv, float scale) {
    float a = fabsf(wv) / scale;
    float q;
    if      (a <= 0.25f) q = 0.0f;
    else if (a <  1.0f ) q = 0.5f;
    else if (a <= 1.25f) q = 1.0f;
    else if (a <  2.0f ) q = 1.5f;
    else if (a <= 2.5f ) q = 2.0f;
    else if (a <  4.0f ) q = 3.0f;
    else if (a <= 5.0f ) q = 4.0f;
    else                 q = 6.0f;
    float d = q * scale;
    return wv < 0.0f ? -d : d;
}

// Fused prep: blocks [0,2048) convert x f32->bf16; blocks [2048,4096) quantize w.
__global__ __launch_bounds__(256) void prep_kernel(const float* __restrict__ w,
                                                   unsigned short* __restrict__ wb,
                                                   const float* __restrict__ x,
                                                   unsigned short* __restrict__ xb) {
    if (blockIdx.x < 2048) {
        const int total4 = (M_TOT * K_TOT) / 4;
        int stride = 2048 * 256;
        for (int i = blockIdx.x * 256 + threadIdx.x; i < total4; i += stride) {
            float4 v = ((const float4*)x)[i];
            u16x4 o;
            o.x = bf16_rne(v.x); o.y = bf16_rne(v.y);
            o.z = bf16_rne(v.z); o.w = bf16_rne(v.w);
            ((u16x4*)xb)[i] = o;
        }
    } else {
        int wv0 = (blockIdx.x - 2048) * 4 + (threadIdx.x >> 6);
        int lane = threadIdx.x & 63;
        const int ngroups = (N_TOT * K_TOT) / 128;   // 131072
        for (int g = wv0; g < ngroups; g += 2048 * 4) {
            size_t base = (size_t)g * 128;
            float2 v = ((const float2*)(w + base))[lane];
            float mx = fmaxf(fabsf(v.x), fabsf(v.y));
            #pragma unroll
            for (int off = 32; off; off >>= 1) mx = fmaxf(mx, __shfl_xor(mx, off));
            float scale = fmaxf(mx / 6.0f, 1e-8f);
            u16x2 o;
            o.x = bf16_rne(fp4_qdq(v.x, scale));
            o.y = bf16_rne(fp4_qdq(v.y, scale));
            *(u16x2*)(wb + base + (size_t)lane * 2) = o;
        }
    }
}

// ---- 256x256 8-phase GEMM (R3/R6 skeleton + tile-top hoisted ds_reads) ----
// C[m][n] = sum_k A[m][k]*B[n][k] + bias[n]; A,B bf16 K-contig, C f32.
// 512 threads = 8 waves (2M x 4N). BK=64 split into k-halves of 32.
// LDS: A regions at [BB*32768 + KK*16384], B at +65536; [256 rows][32 cols]
// bf16, rotation swizzle (pos p holds src granule (p-(r>>1))&3).
// ALL 24 ds_reads of a K-tile issue at ph1-top (regions published by the
// vmcnt(6)+BAR at end of previous tile's ph4) -> ph2-ph4 have zero lgkm stall.
// Overwrite-hazard ledger (consumed-at-MFMA-issue < following BAR < stage):
//  Bk0: consumed ph1 < ph2 stage | Ak0: ph2 < ph3 | Bk1: ph3 < ph4 | Ak1: ph4 < u+1 ph1.
// Barriers and vmcnt positions identical to the R3-verified template.

#define BAR()      __builtin_amdgcn_s_barrier()
#define SCHEDB()   __builtin_amdgcn_sched_barrier(0)
#define WAITVM6()  asm volatile("s_waitcnt vmcnt(6)" ::: "memory")
#define WAITVM0()  asm volatile("s_waitcnt vmcnt(0)" ::: "memory")

__global__ __launch_bounds__(512) void gemm_kernel(const unsigned short* __restrict__ A,
                                                   const unsigned short* __restrict__ B,
                                                   const float* __restrict__ bias,
                                                   float* __restrict__ C) {
    extern __shared__ unsigned char lds[];   // 131072 bytes

    // 2D-chunked XCD swizzle: XCD = bid&7 owns a 16tm x 4tn rectangle;
    // its 32 concurrently-resident blocks cover 8tm x 4tn -> L2 set ~384KB.
    const int bid = blockIdx.x;
    const int xcd = bid & 7;
    const int idx = bid >> 3;          // 0..63
    const int tm = ((xcd >> 2) << 4) + (idx >> 2);   // 0..31
    const int tn = ((xcd & 3) << 2) + (idx & 3);     // 0..15
    const int m0 = tm << 8, n0 = tn << 8;

    const int t = threadIdx.x;
    const int l = t & 63;
    const int wid = t >> 6;
    const int wr = wid >> 2;   // 0..1
    const int wc = wid & 3;    // 0..3
    const int l15 = l & 15;
    const int q4 = l >> 4;

    // Precomputed LDS read bases (rotation swizzle baked in).
    unsigned offA[8];   // [QM*4+i]
    #pragma unroll
    for (int QM = 0; QM < 2; ++QM)
        #pragma unroll
        for (int i = 0; i < 4; ++i) {
            int ra = wr * 128 + QM * 64 + i * 16 + l15;
            unsigned pa = (unsigned)((q4 + (ra >> 1)) & 3);
            offA[QM * 4 + i] = (unsigned)ra * 64u + pa * 16u;
        }
    unsigned offB[4];   // [n], B matrix base +65536 baked in
    #pragma unroll
    for (int n = 0; n < 4; ++n) {
        int rb = wc * 64 + n * 16 + l15;
        unsigned pb = (unsigned)((q4 + (rb >> 1)) & 3);
        offB[n] = 65536u + (unsigned)rb * 64u + pb * 16u;
    }

    // Staging: thread t covers granules G0=t, G1=512+t of each 1024-granule region.
    const int r0g = t >> 2,        p0g = t & 3;
    const int r1g = (512 + t) >> 2, p1g = t & 3;
    const int s0g = (p0g - (r0g >> 1)) & 3;
    const int s1g = (p1g - (r1g >> 1)) & 3;
    const unsigned short* arow0 = A + (size_t)(m0 + r0g) * K_TOT + s0g * 8;
    const unsigned short* arow1 = A + (size_t)(m0 + r1g) * K_TOT + s1g * 8;
    const unsigned short* brow0 = B + (size_t)(n0 + r0g) * K_TOT + s0g * 8;
    const unsigned short* brow1 = B + (size_t)(n0 + r1g) * K_TOT + s1g * 8;
    const unsigned lo0 = (unsigned)t * 16u;
    const unsigned lo1 = lo0 + 8192u;

// Region base: MAT(A=0,B=65536) + BB*32768 + KK*16384.
#define STAGE(ROW0, ROW1, MATOFF, KK, TT, BB) do {                                   \
      const unsigned _base = (MATOFF) + (unsigned)(BB) * 32768u + (KK) * 16384u;     \
      const int _ko = (TT) * 64 + (KK) * 32;                                         \
      __builtin_amdgcn_global_load_lds((gas1)(ROW0 + _ko), (las3)(lds + _base + lo0), 16, 0, 0); \
      __builtin_amdgcn_global_load_lds((gas1)(ROW1 + _ko), (las3)(lds + _base + lo1), 16, 0, 0); \
    } while (0)
#define STAGE_A(KK, TT, BB) STAGE(arow0, arow1, 0u, KK, TT, BB)
#define STAGE_B(KK, TT, BB) STAGE(brow0, brow1, 65536u, KK, TT, BB)

// Hoisted: all 24 ds_reads of the tile, consumption-ordered.
// af[KK*8+QM*4+i], bg[KK*4+n].
#define LOADALL(BB) do {                                                             \
      _Pragma("unroll")                                                              \
      for (int n = 0; n < 4; ++n)                                                    \
        bg[n] = *(const bf16x8*)(lds + ((BB) * 32768u) + offB[n]);                   \
      _Pragma("unroll")                                                              \
      for (int i = 0; i < 4; ++i)                                                    \
        af[i] = *(const bf16x8*)(lds + ((BB) * 32768u) + offA[i]);                   \
      _Pragma("unroll")                                                              \
      for (int i = 0; i < 4; ++i)                                                    \
        af[4 + i] = *(const bf16x8*)(lds + ((BB) * 32768u) + offA[4 + i]);           \
      _Pragma("unroll")                                                              \
      for (int n = 0; n < 4; ++n)                                                    \
        bg[4 + n] = *(const bf16x8*)(lds + ((BB) * 32768u + 16384u) + offB[n]);      \
      _Pragma("unroll")                                                              \
      for (int i = 0; i < 4; ++i)                                                    \
        af[8 + i] = *(const bf16x8*)(lds + ((BB) * 32768u + 16384u) + offA[i]);      \
      _Pragma("unroll")                                                              \
      for (int i = 0; i < 4; ++i)                                                    \
        af[12 + i] = *(const bf16x8*)(lds + ((BB) * 32768u + 16384u) + offA[4 + i]); \
    } while (0)

#define MFMA16(QM, KK) do {                                                          \
      _Pragma("unroll")                                                              \
      for (int i = 0; i < 4; ++i)                                                    \
        _Pragma("unroll")                                                            \
        for (int n = 0; n < 4; ++n)                                                  \
          acc[(QM) * 4 + i][n] = __builtin_amdgcn_mfma_f32_16x16x32_bf16(            \
              af[(KK) * 8 + (QM) * 4 + i], bg[(KK) * 4 + n],                         \
              acc[(QM) * 4 + i][n], 0, 0, 0);                                        \
    } while (0)

// One K-tile = 4 phases (R3 sync structure; reads hoisted to ph1-top).
#define KTILE(U, BB) do {                                                            \
      const int tt1 = ((U) + 1 < NTILE) ? (U) + 1 : (U) - 1;                         \
      const int tt2 = ((U) + 2 < NTILE) ? (U) + 2 : (U);                             \
      /* phase 1: kk=0 qm=0 */                                                       \
      LOADALL(BB); SCHEDB();                                                         \
      STAGE_A(1, tt1, 1 - (BB));                                                     \
      BAR();                                                                         \
      __builtin_amdgcn_s_setprio(1); MFMA16(0, 0); __builtin_amdgcn_s_setprio(0);    \
      BAR();                                                                         \
      /* phase 2: kk=0 qm=1 */                                                       \
      STAGE_B(0, tt2, BB);                                                           \
      BAR();                                                                         \
      __builtin_amdgcn_s_setprio(1); MFMA16(1, 0); __builtin_amdgcn_s_setprio(0);    \
      BAR();                                                                         \
      /* phase 3: kk=1 qm=0 */                                                       \
      STAGE_A(0, tt2, BB);                                                           \
      BAR();                                                                         \
      __builtin_amdgcn_s_setprio(1); MFMA16(0, 1); __builtin_amdgcn_s_setprio(0);    \
      BAR();                                                                         \
      /* phase 4: kk=1 qm=1 */                                                       \
      STAGE_B(1, tt2, BB);                                                           \
      BAR();                                                                         \
      __builtin_amdgcn_s_setprio(1); MFMA16(1, 1); __builtin_amdgcn_s_setprio(0);    \
      WAITVM6(); SCHEDB(); BAR();                                                    \
    } while (0)

    f32x4 acc[8][4];
    #pragma unroll
    for (int i = 0; i < 8; ++i)
        #pragma unroll
        for (int j = 0; j < 4; ++j)
            acc[i][j] = (f32x4)0.0f;
    bf16x8 af[16], bg[8];

    // Prologue: tile0 {Ak0,Bk0,Ak1,Bk1}, tile1 {Ak0,Bk0,Bk1}; 14 issued,
    // need first 8 (all of tile 0) -> vmcnt(6).
    STAGE_A(0, 0, 0); STAGE_B(0, 0, 0); STAGE_A(1, 0, 0); STAGE_B(1, 0, 0);
    STAGE_A(0, 1, 1); STAGE_B(0, 1, 1); STAGE_B(1, 1, 1);
    WAITVM6(); SCHEDB();
    BAR();

    #pragma unroll 1
    for (int u = 0; u < NTILE; u += 2) {
        KTILE(u, 0);
        KTILE(u + 1, 1);
    }
    WAITVM0();   // drain idempotent tail reloads before LDS dealloc

    // Epilogue: C/D layout col=lane&15, row=(lane>>4)*4+reg
    #pragma unroll
    for (int j = 0; j < 4; ++j) {
        int n = n0 + wc * 64 + j * 16 + l15;
        float bv = bias[n];
        #pragma unroll
        for (int i = 0; i < 8; ++i) {
            int mb = m0 + wr * 128 + i * 16 + (q4 << 2);
            #pragma unroll
            for (int r = 0; r < 4; ++r)
                C[(size_t)(mb + r) * N_TOT + n] = acc[i][j][r] + bv;
        }
    }
}

extern "C" void kernel_launch(void* const* d_in, const int* in_sizes, int n_in,
                              void* d_out, int out_size, void* d_ws, size_t ws_size,
                              hipStream_t stream) {
    const float* x    = (const float*)d_in[0];
    const float* w    = (const float*)d_in[1];
    const float* bias = (const float*)d_in[2];
    float* out = (float*)d_out;

    unsigned short* wb = (unsigned short*)d_ws;                      // 32 MiB
    unsigned short* xb = wb + (size_t)N_TOT * K_TOT;                 // +64 MiB

    prep_kernel<<<4096, 256, 0, stream>>>(w, wb, x, xb);

    hipFuncSetAttribute(reinterpret_cast<const void*>(gemm_kernel),
                        hipFuncAttributeMaxDynamicSharedMemorySize, 131072);
    gemm_kernel<<<512, 512, 131072, stream>>>(xb, wb, bias, out);
}

// Round 9
// 293.757 us; speedup vs baseline: 1.0153x; 1.0153x over previous
//
#include <hip/hip_runtime.h>
#include <stdint.h>

#define M_TOT 8192
#define N_TOT 4096
#define K_TOT 4096
#define NTILE 64   // K-tiles of BK=64

typedef __attribute__((ext_vector_type(8))) short bf16x8;
typedef __attribute__((ext_vector_type(4))) float f32x4;
typedef __attribute__((ext_vector_type(2))) unsigned short u16x2;
typedef __attribute__((ext_vector_type(4))) unsigned short u16x4;

typedef const __attribute__((address_space(1))) void* gas1;
typedef __attribute__((address_space(3))) void* las3;

__device__ __forceinline__ unsigned short bf16_rne(float f) {
    union { float f; unsigned int u; } v; v.f = f;
    unsigned int u = v.u;
    return (unsigned short)((u + 0x7FFFu + ((u >> 16) & 1u)) >> 16);
}

// Exact collapse of the reference FP4(E2M1) quant-dequant on a = |w|/scale.
__device__ __forceinline__ float fp4_qdq(float wv, float scale) {
    float a = fabsf(wv) / scale;
    float q;
    if      (a <= 0.25f) q = 0.0f;
    else if (a <  1.0f ) q = 0.5f;
    else if (a <= 1.25f) q = 1.0f;
    else if (a <  2.0f ) q = 1.5f;
    else if (a <= 2.5f ) q = 2.0f;
    else if (a <  4.0f ) q = 3.0f;
    else if (a <= 5.0f ) q = 4.0f;
    else                 q = 6.0f;
    float d = q * scale;
    return wv < 0.0f ? -d : d;
}

// Fused prep: blocks [0,2048) convert x f32->bf16; blocks [2048,4096) quantize w.
__global__ __launch_bounds__(256) void prep_kernel(const float* __restrict__ w,
                                                   unsigned short* __restrict__ wb,
                                                   const float* __restrict__ x,
                                                   unsigned short* __restrict__ xb) {
    if (blockIdx.x < 2048) {
        const int total4 = (M_TOT * K_TOT) / 4;
        int stride = 2048 * 256;
        for (int i = blockIdx.x * 256 + threadIdx.x; i < total4; i += stride) {
            float4 v = ((const float4*)x)[i];
            u16x4 o;
            o.x = bf16_rne(v.x); o.y = bf16_rne(v.y);
            o.z = bf16_rne(v.z); o.w = bf16_rne(v.w);
            ((u16x4*)xb)[i] = o;
        }
    } else {
        int wv0 = (blockIdx.x - 2048) * 4 + (threadIdx.x >> 6);
        int lane = threadIdx.x & 63;
        const int ngroups = (N_TOT * K_TOT) / 128;   // 131072
        for (int g = wv0; g < ngroups; g += 2048 * 4) {
            size_t base = (size_t)g * 128;
            float2 v = ((const float2*)(w + base))[lane];
            float mx = fmaxf(fabsf(v.x), fabsf(v.y));
            #pragma unroll
            for (int off = 32; off; off >>= 1) mx = fmaxf(mx, __shfl_xor(mx, off));
            float scale = fmaxf(mx / 6.0f, 1e-8f);
            u16x2 o;
            o.x = bf16_rne(fp4_qdq(v.x, scale));
            o.y = bf16_rne(fp4_qdq(v.y, scale));
            *(u16x2*)(wb + base + (size_t)lane * 2) = o;
        }
    }
}

// ------ 256x256 GEMM, 2 phases x 32 MFMA per K-tile (merged from R3/R6) ------
// C[m][n] = sum_k A[m][k]*B[n][k] + bias[n]; A,B bf16 K-contig, C f32.
// 512 threads = 8 waves (2M x 4N). BK=64 split into k-halves of 32.
// LDS: A regions at [BB*32768 + KK*16384], B at +65536; [256 rows][32 cols]
// bf16, rotation swizzle (pos p holds src granule (p-(r>>1))&3).
//
// Per K-tile u (buffer BB):
//  P1: read Ak0,Bk0(BB) [12 ds_reads]; stage Ak1(u+1),Bk1(u+1)->buf^1;
//      BAR; 32 MFMA (kk=0, qm=0+1); vmcnt(8); BAR.
//  P2: read Ak1,Bk1(BB); stage Ak0(u+2),Bk0(u+2)->BB;
//      BAR; 32 MFMA (kk=1); vmcnt(8); BAR.
// Slot-overwrite ledger (last-read drains via lgkm before the BAR preceding
// the overwriting stage):
//  P1 stages Ak1/Bk1(u+1)->buf^1: old Ak1/Bk1(u-1) last read P2(u-1), BAR between. OK
//  P2 stages Ak0/Bk0(u+2)->BB:    old Ak0/Bk0(u)   last read P1(u),   BAR between. OK
// In-phase: P1 reads BB k0-slots, stages buf^1 k1-slots (disjoint); P2 reads
// BB k1-slots, stages BB k0-slots (disjoint).
// vmcnt(8): stage groups are 4 insts/phase; the region needed next phase is
// always the 9th..12th-newest load => vmcnt(8) at the end of EVERY phase
// (prologue issues 12, first 4 needed -> vmcnt(8) uniform; never 0 in loop).

#define BAR()      __builtin_amdgcn_s_barrier()
#define SCHEDB()   __builtin_amdgcn_sched_barrier(0)
#define WAITVM8()  asm volatile("s_waitcnt vmcnt(8)" ::: "memory")
#define WAITVM0()  asm volatile("s_waitcnt vmcnt(0)" ::: "memory")

__global__ __launch_bounds__(512) void gemm_kernel(const unsigned short* __restrict__ A,
                                                   const unsigned short* __restrict__ B,
                                                   const float* __restrict__ bias,
                                                   float* __restrict__ C) {
    extern __shared__ unsigned char lds[];   // 131072 bytes

    // 2D-chunked XCD swizzle: XCD = bid&7 owns a 16tm x 4tn rectangle;
    // its 32 concurrently-resident blocks cover 8tm x 4tn -> L2 set ~384KB.
    const int bid = blockIdx.x;
    const int xcd = bid & 7;
    const int idx = bid >> 3;          // 0..63
    const int tm = ((xcd >> 2) << 4) + (idx >> 2);   // 0..31
    const int tn = ((xcd & 3) << 2) + (idx & 3);     // 0..15
    const int m0 = tm << 8, n0 = tn << 8;

    const int t = threadIdx.x;
    const int l = t & 63;
    const int wid = t >> 6;
    const int wr = wid >> 2;   // 0..1
    const int wc = wid & 3;    // 0..3
    const int l15 = l & 15;
    const int q4 = l >> 4;

    // Precomputed LDS read bases (rotation swizzle baked in).
    unsigned offA[8];   // [QM*4+i]
    #pragma unroll
    for (int QM = 0; QM < 2; ++QM)
        #pragma unroll
        for (int i = 0; i < 4; ++i) {
            int ra = wr * 128 + QM * 64 + i * 16 + l15;
            unsigned pa = (unsigned)((q4 + (ra >> 1)) & 3);
            offA[QM * 4 + i] = (unsigned)ra * 64u + pa * 16u;
        }
    unsigned offB[4];   // [n], B matrix base +65536 baked in
    #pragma unroll
    for (int n = 0; n < 4; ++n) {
        int rb = wc * 64 + n * 16 + l15;
        unsigned pb = (unsigned)((q4 + (rb >> 1)) & 3);
        offB[n] = 65536u + (unsigned)rb * 64u + pb * 16u;
    }

    // Staging: thread t covers granules G0=t, G1=512+t of each 1024-granule region.
    const int r0g = t >> 2,        p0g = t & 3;
    const int r1g = (512 + t) >> 2, p1g = t & 3;
    const int s0g = (p0g - (r0g >> 1)) & 3;
    const int s1g = (p1g - (r1g >> 1)) & 3;
    const unsigned short* arow0 = A + (size_t)(m0 + r0g) * K_TOT + s0g * 8;
    const unsigned short* arow1 = A + (size_t)(m0 + r1g) * K_TOT + s1g * 8;
    const unsigned short* brow0 = B + (size_t)(n0 + r0g) * K_TOT + s0g * 8;
    const unsigned short* brow1 = B + (size_t)(n0 + r1g) * K_TOT + s1g * 8;
    const unsigned lo0 = (unsigned)t * 16u;
    const unsigned lo1 = lo0 + 8192u;

// Region base: MAT(A=0,B=65536) + BB*32768 + KK*16384.
#define STAGE(ROW0, ROW1, MATOFF, KK, TT, BB) do {                                   \
      const unsigned _base = (MATOFF) + (unsigned)(BB) * 32768u + (KK) * 16384u;     \
      const int _ko = (TT) * 64 + (KK) * 32;                                         \
      __builtin_amdgcn_global_load_lds((gas1)(ROW0 + _ko), (las3)(lds + _base + lo0), 16, 0, 0); \
      __builtin_amdgcn_global_load_lds((gas1)(ROW1 + _ko), (las3)(lds + _base + lo1), 16, 0, 0); \
    } while (0)
#define STAGE_A(KK, TT, BB) STAGE(arow0, arow1, 0u, KK, TT, BB)
#define STAGE_B(KK, TT, BB) STAGE(brow0, brow1, 65536u, KK, TT, BB)

#define LOAD_A(QM, KK, BB) do {                                                      \
      _Pragma("unroll")                                                              \
      for (int i = 0; i < 4; ++i)                                                    \
        af[(QM) * 4 + i] = *(const bf16x8*)(lds + ((BB) * 32768u + (KK) * 16384u)    \
                                            + offA[(QM) * 4 + i]);                   \
    } while (0)

#define LOAD_B(KK, BB) do {                                                          \
      _Pragma("unroll")                                                              \
      for (int n = 0; n < 4; ++n)                                                    \
        bg[n] = *(const bf16x8*)(lds + ((BB) * 32768u + (KK) * 16384u) + offB[n]);   \
    } while (0)

#define MFMA16(QM) do {                                                              \
      _Pragma("unroll")                                                              \
      for (int i = 0; i < 4; ++i)                                                    \
        _Pragma("unroll")                                                            \
        for (int n = 0; n < 4; ++n)                                                  \
          acc[(QM) * 4 + i][n] = __builtin_amdgcn_mfma_f32_16x16x32_bf16(            \
              af[(QM) * 4 + i], bg[n], acc[(QM) * 4 + i][n], 0, 0, 0);               \
    } while (0)

// One K-tile = 2 phases of 32 MFMA.
#define KTILE(U, BB) do {                                                            \
      const int tt1 = ((U) + 1 < NTILE) ? (U) + 1 : (U) - 1;                         \
      const int tt2 = ((U) + 2 < NTILE) ? (U) + 2 : (U);                             \
      /* P1: kk=0, qm=0+1 */                                                         \
      LOAD_B(0, BB); LOAD_A(0, 0, BB); LOAD_A(1, 0, BB);                             \
      STAGE_A(1, tt1, 1 - (BB)); STAGE_B(1, tt1, 1 - (BB));                          \
      BAR();                                                                         \
      __builtin_amdgcn_s_setprio(1); MFMA16(0); MFMA16(1);                           \
      __builtin_amdgcn_s_setprio(0);                                                 \
      WAITVM8(); SCHEDB(); BAR();                                                    \
      /* P2: kk=1, qm=0+1 */                                                         \
      LOAD_B(1, BB); LOAD_A(0, 1, BB); LOAD_A(1, 1, BB);                             \
      STAGE_A(0, tt2, BB); STAGE_B(0, tt2, BB);                                      \
      BAR();                                                                         \
      __builtin_amdgcn_s_setprio(1); MFMA16(0); MFMA16(1);                           \
      __builtin_amdgcn_s_setprio(0);                                                 \
      WAITVM8(); SCHEDB(); BAR();                                                    \
    } while (0)

    f32x4 acc[8][4];
    #pragma unroll
    for (int i = 0; i < 8; ++i)
        #pragma unroll
        for (int j = 0; j < 4; ++j)
            acc[i][j] = (f32x4)0.0f;
    bf16x8 af[8], bg[4];

    // Prologue stages (12 load-insts): tile0 {Ak0,Bk0,Ak1,Bk1}->buf0,
    // tile1 {Ak0,Bk0}->buf1. P1(0) needs the first 4 -> vmcnt(8).
    STAGE_A(0, 0, 0); STAGE_B(0, 0, 0); STAGE_A(1, 0, 0); STAGE_B(1, 0, 0);
    STAGE_A(0, 1, 1); STAGE_B(0, 1, 1);
    WAITVM8(); SCHEDB();
    BAR();

    #pragma unroll 1
    for (int u = 0; u < NTILE; u += 2) {
        KTILE(u, 0);
        KTILE(u + 1, 1);
    }
    WAITVM0();   // drain idempotent tail reloads before LDS dealloc

    // Epilogue: C/D layout col=lane&15, row=(lane>>4)*4+reg
    #pragma unroll
    for (int j = 0; j < 4; ++j) {
        int n = n0 + wc * 64 + j * 16 + l15;
        float bv = bias[n];
        #pragma unroll
        for (int i = 0; i < 8; ++i) {
            int mb = m0 + wr * 128 + i * 16 + (q4 << 2);
            #pragma unroll
            for (int r = 0; r < 4; ++r)
                C[(size_t)(mb + r) * N_TOT + n] = acc[i][j][r] + bv;
        }
    }
}

extern "C" void kernel_launch(void* const* d_in, const int* in_sizes, int n_in,
                              void* d_out, int out_size, void* d_ws, size_t ws_size,
                              hipStream_t stream) {
    const float* x    = (const float*)d_in[0];
    const float* w    = (const float*)d_in[1];
    const float* bias = (const float*)d_in[2];
    float* out = (float*)d_out;

    unsigned short* wb = (unsigned short*)d_ws;                      // 32 MiB
    unsigned short* xb = wb + (size_t)N_TOT * K_TOT;                 // +64 MiB

    prep_kernel<<<4096, 256, 0, stream>>>(w, wb, x, xb);

    hipFuncSetAttribute(reinterpret_cast<const void*>(gemm_kernel),
                        hipFuncAttributeMaxDynamicSharedMemorySize, 131072);
    gemm_kernel<<<512, 512, 131072, stream>>>(xb, wb, bias, out);
}

// Round 10
// 289.735 us; speedup vs baseline: 1.0294x; 1.0139x over previous
//
#include <hip/hip_runtime.h>
#include <stdint.h>

#define M_TOT 8192
#define N_TOT 4096
#define K_TOT 4096
#define NTILE 64   // K-tiles of BK=64

typedef __attribute__((ext_vector_type(8))) short bf16x8;
typedef __attribute__((ext_vector_type(4))) float f32x4;
typedef __attribute__((ext_vector_type(2))) unsigned short u16x2;
typedef __attribute__((ext_vector_type(4))) unsigned short u16x4;

typedef const __attribute__((address_space(1))) void* gas1;
typedef __attribute__((address_space(3))) void* las3;

__device__ __forceinline__ unsigned short bf16_rne(float f) {
    union { float f; unsigned int u; } v; v.f = f;
    unsigned int u = v.u;
    return (unsigned short)((u + 0x7FFFu + ((u >> 16) & 1u)) >> 16);
}

// Exact collapse of the reference FP4(E2M1) quant-dequant on a = |w|/scale.
__device__ __forceinline__ float fp4_qdq(float wv, float scale) {
    float a = fabsf(wv) / scale;
    float q;
    if      (a <= 0.25f) q = 0.0f;
    else if (a <  1.0f ) q = 0.5f;
    else if (a <= 1.25f) q = 1.0f;
    else if (a <  2.0f ) q = 1.5f;
    else if (a <= 2.5f ) q = 2.0f;
    else if (a <  4.0f ) q = 3.0f;
    else if (a <= 5.0f ) q = 4.0f;
    else                 q = 6.0f;
    float d = q * scale;
    return wv < 0.0f ? -d : d;
}

// Fused prep: blocks [0,2048) convert x f32->bf16; blocks [2048,4096) quantize w.
__global__ __launch_bounds__(256) void prep_kernel(const float* __restrict__ w,
                                                   unsigned short* __restrict__ wb,
                                                   const float* __restrict__ x,
                                                   unsigned short* __restrict__ xb) {
    if (blockIdx.x < 2048) {
        const int total4 = (M_TOT * K_TOT) / 4;
        int stride = 2048 * 256;
        for (int i = blockIdx.x * 256 + threadIdx.x; i < total4; i += stride) {
            float4 v = ((const float4*)x)[i];
            u16x4 o;
            o.x = bf16_rne(v.x); o.y = bf16_rne(v.y);
            o.z = bf16_rne(v.z); o.w = bf16_rne(v.w);
            ((u16x4*)xb)[i] = o;
        }
    } else {
        int wv0 = (blockIdx.x - 2048) * 4 + (threadIdx.x >> 6);
        int lane = threadIdx.x & 63;
        const int ngroups = (N_TOT * K_TOT) / 128;   // 131072
        for (int g = wv0; g < ngroups; g += 2048 * 4) {
            size_t base = (size_t)g * 128;
            float2 v = ((const float2*)(w + base))[lane];
            float mx = fmaxf(fabsf(v.x), fabsf(v.y));
            #pragma unroll
            for (int off = 32; off; off >>= 1) mx = fmaxf(mx, __shfl_xor(mx, off));
            float scale = fmaxf(mx / 6.0f, 1e-8f);
            u16x2 o;
            o.x = bf16_rne(fp4_qdq(v.x, scale));
            o.y = bf16_rne(fp4_qdq(v.y, scale));
            *(u16x2*)(wb + base + (size_t)lane * 2) = o;
        }
    }
}

// --- 256x256 8-phase GEMM (R3/R6 skeleton; reads issued under prior MFMA) ---
// C[m][n] = sum_k A[m][k]*B[n][k] + bias[n]; A,B bf16 K-contig, C f32.
// 512 threads = 8 waves (2M x 4N). BK=64 split into k-halves of 32.
// LDS: A regions at [BB*32768 + KK*16384], B at +65536; [256 rows][32 cols]
// bf16, rotation swizzle (pos p holds src granule (p-(r>>1))&3).
//
// Sync structure (barriers/stages/vmcnt) IDENTICAL to the R3-verified
// template. Only ds_read issue points move: each phase's reads issue inside
// the PREVIOUS phase's MFMA section (post-MFMA-issue, pre-closing-BAR), where
// they execute under the MFMA pipe tail. ph1's reads stay at ph1-top (its
// regions are published only by the vmcnt(6)+BAR ending ph4(u-1)).
// Publication audit (read-issue point is after region's staging covered by a
// vmcnt + barrier on ALL waves):
//  ph1-post reads Ak0q1(u): Ak0(u) staged ph3(u-2), publ. end-ph4(u-1). OK
//  ph2-post reads Bk1(u),Ak1q0(u): staged ph4(u-2)/ph1(u-1); the end-ph4(u-1)
//    vmcnt(6) has exactly 6 younger loads than Ak1(u)'s stage. OK
//  ph3-post reads Ak1q1(u): same region as above. OK
// Overwrite audit (read drains >=1 barrier before the overwriting stage):
//  Ak0q1 read (ph1-post) drains by ph2 MFMA < ph3 stage Ak0(u+2). OK
//  Bk1 read (ph2-post) drains by ph3 MFMA < ph4 stage Bk1(u+2). OK
//  Ak1 reads (ph2/ph3-post) drain by ph3/ph4 MFMA < ph1(u+1) stage. OK

#define BAR()      __builtin_amdgcn_s_barrier()
#define SCHEDB()   __builtin_amdgcn_sched_barrier(0)
#define WAITVM6()  asm volatile("s_waitcnt vmcnt(6)" ::: "memory")
#define WAITVM0()  asm volatile("s_waitcnt vmcnt(0)" ::: "memory")

__global__ __launch_bounds__(512) void gemm_kernel(const unsigned short* __restrict__ A,
                                                   const unsigned short* __restrict__ B,
                                                   const float* __restrict__ bias,
                                                   float* __restrict__ C) {
    extern __shared__ unsigned char lds[];   // 131072 bytes

    // 2D-chunked XCD swizzle: XCD = bid&7 owns a 16tm x 4tn rectangle;
    // its 32 concurrently-resident blocks cover 8tm x 4tn -> L2 set ~384KB.
    const int bid = blockIdx.x;
    const int xcd = bid & 7;
    const int idx = bid >> 3;          // 0..63
    const int tm = ((xcd >> 2) << 4) + (idx >> 2);   // 0..31
    const int tn = ((xcd & 3) << 2) + (idx & 3);     // 0..15
    const int m0 = tm << 8, n0 = tn << 8;

    const int t = threadIdx.x;
    const int l = t & 63;
    const int wid = t >> 6;
    const int wr = wid >> 2;   // 0..1
    const int wc = wid & 3;    // 0..3
    const int l15 = l & 15;
    const int q4 = l >> 4;

    // Precomputed LDS read bases (rotation swizzle baked in).
    unsigned offA[8];   // [QM*4+i]
    #pragma unroll
    for (int QM = 0; QM < 2; ++QM)
        #pragma unroll
        for (int i = 0; i < 4; ++i) {
            int ra = wr * 128 + QM * 64 + i * 16 + l15;
            unsigned pa = (unsigned)((q4 + (ra >> 1)) & 3);
            offA[QM * 4 + i] = (unsigned)ra * 64u + pa * 16u;
        }
    unsigned offB[4];   // [n], B matrix base +65536 baked in
    #pragma unroll
    for (int n = 0; n < 4; ++n) {
        int rb = wc * 64 + n * 16 + l15;
        unsigned pb = (unsigned)((q4 + (rb >> 1)) & 3);
        offB[n] = 65536u + (unsigned)rb * 64u + pb * 16u;
    }

    // Staging: thread t covers granules G0=t, G1=512+t of each 1024-granule region.
    const int r0g = t >> 2,        p0g = t & 3;
    const int r1g = (512 + t) >> 2, p1g = t & 3;
    const int s0g = (p0g - (r0g >> 1)) & 3;
    const int s1g = (p1g - (r1g >> 1)) & 3;
    const unsigned short* arow0 = A + (size_t)(m0 + r0g) * K_TOT + s0g * 8;
    const unsigned short* arow1 = A + (size_t)(m0 + r1g) * K_TOT + s1g * 8;
    const unsigned short* brow0 = B + (size_t)(n0 + r0g) * K_TOT + s0g * 8;
    const unsigned short* brow1 = B + (size_t)(n0 + r1g) * K_TOT + s1g * 8;
    const unsigned lo0 = (unsigned)t * 16u;
    const unsigned lo1 = lo0 + 8192u;

// Region base: MAT(A=0,B=65536) + BB*32768 + KK*16384.
#define STAGE(ROW0, ROW1, MATOFF, KK, TT, BB) do {                                   \
      const unsigned _base = (MATOFF) + (unsigned)(BB) * 32768u + (KK) * 16384u;     \
      const int _ko = (TT) * 64 + (KK) * 32;                                         \
      __builtin_amdgcn_global_load_lds((gas1)(ROW0 + _ko), (las3)(lds + _base + lo0), 16, 0, 0); \
      __builtin_amdgcn_global_load_lds((gas1)(ROW1 + _ko), (las3)(lds + _base + lo1), 16, 0, 0); \
    } while (0)
#define STAGE_A(KK, TT, BB) STAGE(arow0, arow1, 0u, KK, TT, BB)
#define STAGE_B(KK, TT, BB) STAGE(brow0, brow1, 65536u, KK, TT, BB)

#define LOAD_A4(DST, QM, KK, BB) do {                                                \
      _Pragma("unroll")                                                              \
      for (int i = 0; i < 4; ++i)                                                    \
        DST[i] = *(const bf16x8*)(lds + ((BB) * 32768u + (KK) * 16384u)              \
                                  + offA[(QM) * 4 + i]);                             \
    } while (0)

#define LOAD_B4(DST, KK, BB) do {                                                    \
      _Pragma("unroll")                                                              \
      for (int n = 0; n < 4; ++n)                                                    \
        DST[n] = *(const bf16x8*)(lds + ((BB) * 32768u + (KK) * 16384u) + offB[n]);  \
    } while (0)

#define MFMA16(QM, AF, BG) do {                                                      \
      _Pragma("unroll")                                                              \
      for (int i = 0; i < 4; ++i)                                                    \
        _Pragma("unroll")                                                            \
        for (int n = 0; n < 4; ++n)                                                  \
          acc[(QM) * 4 + i][n] = __builtin_amdgcn_mfma_f32_16x16x32_bf16(            \
              AF[i], BG[n], acc[(QM) * 4 + i][n], 0, 0, 0);                          \
    } while (0)

// One K-tile = 4 phases; stages/barriers/vmcnt exactly as R3/R6.
// Frag sets: af0/af1 (A k-half frags, alternating), bgA (Bk0), bgB (Bk1).
#define KTILE(U, BB) do {                                                            \
      const int tt1 = ((U) + 1 < NTILE) ? (U) + 1 : (U) - 1;                         \
      const int tt2 = ((U) + 2 < NTILE) ? (U) + 2 : (U);                             \
      /* phase 1: kk=0 qm=0 */                                                       \
      LOAD_B4(bgA, 0, BB); LOAD_A4(af0, 0, 0, BB);                                   \
      STAGE_A(1, tt1, 1 - (BB));                                                     \
      BAR();                                                                         \
      __builtin_amdgcn_s_setprio(1); MFMA16(0, af0, bgA);                            \
      __builtin_amdgcn_s_setprio(0);                                                 \
      LOAD_A4(af1, 1, 0, BB); SCHEDB();                                              \
      BAR();                                                                         \
      /* phase 2: kk=0 qm=1 */                                                       \
      STAGE_B(0, tt2, BB);                                                           \
      BAR();                                                                         \
      __builtin_amdgcn_s_setprio(1); MFMA16(1, af1, bgA);                            \
      __builtin_amdgcn_s_setprio(0);                                                 \
      LOAD_B4(bgB, 1, BB); LOAD_A4(af0, 0, 1, BB); SCHEDB();                         \
      BAR();                                                                         \
      /* phase 3: kk=1 qm=0 */                                                       \
      STAGE_A(0, tt2, BB);                                                           \
      BAR();                                                                         \
      __builtin_amdgcn_s_setprio(1); MFMA16(0, af0, bgB);                            \
      __builtin_amdgcn_s_setprio(0);                                                 \
      LOAD_A4(af1, 1, 1, BB); SCHEDB();                                              \
      BAR();                                                                         \
      /* phase 4: kk=1 qm=1 */                                                       \
      STAGE_B(1, tt2, BB);                                                           \
      BAR();                                                                         \
      __builtin_amdgcn_s_setprio(1); MFMA16(1, af1, bgB);                            \
      __builtin_amdgcn_s_setprio(0);                                                 \
      WAITVM6(); SCHEDB(); BAR();                                                    \
    } while (0)

    f32x4 acc[8][4];
    #pragma unroll
    for (int i = 0; i < 8; ++i)
        #pragma unroll
        for (int j = 0; j < 4; ++j)
            acc[i][j] = (f32x4)0.0f;
    bf16x8 af0[4], af1[4], bgA[4], bgB[4];

    // Prologue: tile0 {Ak0,Bk0,Ak1,Bk1}, tile1 {Ak0,Bk0,Bk1}; 14 issued,
    // need first 8 (all of tile 0) -> vmcnt(6).
    STAGE_A(0, 0, 0); STAGE_B(0, 0, 0); STAGE_A(1, 0, 0); STAGE_B(1, 0, 0);
    STAGE_A(0, 1, 1); STAGE_B(0, 1, 1); STAGE_B(1, 1, 1);
    WAITVM6(); SCHEDB();
    BAR();

    #pragma unroll 1
    for (int u = 0; u < NTILE; u += 2) {
        KTILE(u, 0);
        KTILE(u + 1, 1);
    }
    WAITVM0();   // drain idempotent tail reloads before LDS dealloc

    // Epilogue: C/D layout col=lane&15, row=(lane>>4)*4+reg
    #pragma unroll
    for (int j = 0; j < 4; ++j) {
        int n = n0 + wc * 64 + j * 16 + l15;
        float bv = bias[n];
        #pragma unroll
        for (int i = 0; i < 8; ++i) {
            int mb = m0 + wr * 128 + i * 16 + (q4 << 2);
            #pragma unroll
            for (int r = 0; r < 4; ++r)
                C[(size_t)(mb + r) * N_TOT + n] = acc[i][j][r] + bv;
        }
    }
}

extern "C" void kernel_launch(void* const* d_in, const int* in_sizes, int n_in,
                              void* d_out, int out_size, void* d_ws, size_t ws_size,
                              hipStream_t stream) {
    const float* x    = (const float*)d_in[0];
    const float* w    = (const float*)d_in[1];
    const float* bias = (const float*)d_in[2];
    float* out = (float*)d_out;

    unsigned short* wb = (unsigned short*)d_ws;                      // 32 MiB
    unsigned short* xb = wb + (size_t)N_TOT * K_TOT;                 // +64 MiB

    prep_kernel<<<4096, 256, 0, stream>>>(w, wb, x, xb);

    hipFuncSetAttribute(reinterpret_cast<const void*>(gemm_kernel),
                        hipFuncAttributeMaxDynamicSharedMemorySize, 131072);
    gemm_kernel<<<512, 512, 131072, stream>>>(xb, wb, bias, out);
}

// Round 11
// 284.137 us; speedup vs baseline: 1.0497x; 1.0197x over previous
//
#include <hip/hip_runtime.h>
#include <stdint.h>

#define M_TOT 8192
#define N_TOT 4096
#define K_TOT 4096
#define NTILE 64   // K-tiles of BK=64

typedef __attribute__((ext_vector_type(8))) short bf16x8;
typedef __attribute__((ext_vector_type(4))) float f32x4;
typedef __attribute__((ext_vector_type(2))) unsigned short u16x2;
typedef __attribute__((ext_vector_type(4))) unsigned short u16x4;

typedef const __attribute__((address_space(1))) void* gas1;
typedef __attribute__((address_space(3))) void* las3;

__device__ __forceinline__ unsigned short bf16_rne(float f) {
    union { float f; unsigned int u; } v; v.f = f;
    unsigned int u = v.u;
    return (unsigned short)((u + 0x7FFFu + ((u >> 16) & 1u)) >> 16);
}

// Exact collapse of the reference FP4(E2M1) quant-dequant on a = |w|/scale.
__device__ __forceinline__ float fp4_qdq(float wv, float scale) {
    float a = fabsf(wv) / scale;
    float q;
    if      (a <= 0.25f) q = 0.0f;
    else if (a <  1.0f ) q = 0.5f;
    else if (a <= 1.25f) q = 1.0f;
    else if (a <  2.0f ) q = 1.5f;
    else if (a <= 2.5f ) q = 2.0f;
    else if (a <  4.0f ) q = 3.0f;
    else if (a <= 5.0f ) q = 4.0f;
    else                 q = 6.0f;
    float d = q * scale;
    return wv < 0.0f ? -d : d;
}

// Fused prep: blocks [0,2048) convert x f32->bf16; blocks [2048,4096) quantize w.
__global__ __launch_bounds__(256) void prep_kernel(const float* __restrict__ w,
                                                   unsigned short* __restrict__ wb,
                                                   const float* __restrict__ x,
                                                   unsigned short* __restrict__ xb) {
    if (blockIdx.x < 2048) {
        const int total4 = (M_TOT * K_TOT) / 4;
        int stride = 2048 * 256;
        for (int i = blockIdx.x * 256 + threadIdx.x; i < total4; i += stride) {
            float4 v = ((const float4*)x)[i];
            u16x4 o;
            o.x = bf16_rne(v.x); o.y = bf16_rne(v.y);
            o.z = bf16_rne(v.z); o.w = bf16_rne(v.w);
            ((u16x4*)xb)[i] = o;
        }
    } else {
        int wv0 = (blockIdx.x - 2048) * 4 + (threadIdx.x >> 6);
        int lane = threadIdx.x & 63;
        const int ngroups = (N_TOT * K_TOT) / 128;   // 131072
        for (int g = wv0; g < ngroups; g += 2048 * 4) {
            size_t base = (size_t)g * 128;
            float2 v = ((const float2*)(w + base))[lane];
            float mx = fmaxf(fabsf(v.x), fabsf(v.y));
            #pragma unroll
            for (int off = 32; off; off >>= 1) mx = fmaxf(mx, __shfl_xor(mx, off));
            float scale = fmaxf(mx / 6.0f, 1e-8f);
            u16x2 o;
            o.x = bf16_rne(fp4_qdq(v.x, scale));
            o.y = bf16_rne(fp4_qdq(v.y, scale));
            *(u16x2*)(wb + base + (size_t)lane * 2) = o;
        }
    }
}

// --- 256x256 GEMM, 1 barrier per phase (4/K-tile), reads under prior MFMA ---
// C[m][n] = sum_k A[m][k]*B[n][k] + bias[n]; A,B bf16 K-contig, C f32.
// 512 threads = 8 waves (2M x 4N). BK=64 split into k-halves of 32.
// LDS: A regions at [BB*32768 + KK*16384], B at +65536; [256 rows][32 cols]
// bf16, rotation swizzle (pos p holds src granule (p-(r>>1))&3).
//
// Derived from R10 (verified) by removing the pre-MFMA barrier of each phase.
// Safety: (1) publication — ph1's reads are at ph1-top, AFTER the end-ph4(u-1)
// vmcnt(6)+BAR which publishes ALL 4 regions of tile u (Ak1(u): 6 younger
// loads; Bk1(u): 12). ph2-4 operands pre-read under prior MFMA, same regions.
// (2) overwrite — a wave passes its phase-closing BAR only after its MFMA,
// whose lgkm-wait completes that phase's reads; every overwriting stage is in
// a later phase (Bk0: read ph1 < stage ph2 | Ak0: ph2 < ph3 | Bk1: ph3 < ph4
// | Ak1: ph3-post < ph1(u+1)). vmcnt ledger identical to R3..R10.

#define BAR()      __builtin_amdgcn_s_barrier()
#define SCHEDB()   __builtin_amdgcn_sched_barrier(0)
#define WAITVM6()  asm volatile("s_waitcnt vmcnt(6)" ::: "memory")
#define WAITVM0()  asm volatile("s_waitcnt vmcnt(0)" ::: "memory")

__global__ __launch_bounds__(512) void gemm_kernel(const unsigned short* __restrict__ A,
                                                   const unsigned short* __restrict__ B,
                                                   const float* __restrict__ bias,
                                                   float* __restrict__ C) {
    extern __shared__ unsigned char lds[];   // 131072 bytes

    // 2D-chunked XCD swizzle: XCD = bid&7 owns a 16tm x 4tn rectangle;
    // its 32 concurrently-resident blocks cover 8tm x 4tn -> L2 set ~384KB.
    const int bid = blockIdx.x;
    const int xcd = bid & 7;
    const int idx = bid >> 3;          // 0..63
    const int tm = ((xcd >> 2) << 4) + (idx >> 2);   // 0..31
    const int tn = ((xcd & 3) << 2) + (idx & 3);     // 0..15
    const int m0 = tm << 8, n0 = tn << 8;

    const int t = threadIdx.x;
    const int l = t & 63;
    const int wid = t >> 6;
    const int wr = wid >> 2;   // 0..1
    const int wc = wid & 3;    // 0..3
    const int l15 = l & 15;
    const int q4 = l >> 4;

    // Precomputed LDS read bases (rotation swizzle baked in).
    unsigned offA[8];   // [QM*4+i]
    #pragma unroll
    for (int QM = 0; QM < 2; ++QM)
        #pragma unroll
        for (int i = 0; i < 4; ++i) {
            int ra = wr * 128 + QM * 64 + i * 16 + l15;
            unsigned pa = (unsigned)((q4 + (ra >> 1)) & 3);
            offA[QM * 4 + i] = (unsigned)ra * 64u + pa * 16u;
        }
    unsigned offB[4];   // [n], B matrix base +65536 baked in
    #pragma unroll
    for (int n = 0; n < 4; ++n) {
        int rb = wc * 64 + n * 16 + l15;
        unsigned pb = (unsigned)((q4 + (rb >> 1)) & 3);
        offB[n] = 65536u + (unsigned)rb * 64u + pb * 16u;
    }

    // Staging: thread t covers granules G0=t, G1=512+t of each 1024-granule region.
    const int r0g = t >> 2,        p0g = t & 3;
    const int r1g = (512 + t) >> 2, p1g = t & 3;
    const int s0g = (p0g - (r0g >> 1)) & 3;
    const int s1g = (p1g - (r1g >> 1)) & 3;
    const unsigned short* arow0 = A + (size_t)(m0 + r0g) * K_TOT + s0g * 8;
    const unsigned short* arow1 = A + (size_t)(m0 + r1g) * K_TOT + s1g * 8;
    const unsigned short* brow0 = B + (size_t)(n0 + r0g) * K_TOT + s0g * 8;
    const unsigned short* brow1 = B + (size_t)(n0 + r1g) * K_TOT + s1g * 8;
    const unsigned lo0 = (unsigned)t * 16u;
    const unsigned lo1 = lo0 + 8192u;

// Region base: MAT(A=0,B=65536) + BB*32768 + KK*16384.
#define STAGE(ROW0, ROW1, MATOFF, KK, TT, BB) do {                                   \
      const unsigned _base = (MATOFF) + (unsigned)(BB) * 32768u + (KK) * 16384u;     \
      const int _ko = (TT) * 64 + (KK) * 32;                                         \
      __builtin_amdgcn_global_load_lds((gas1)(ROW0 + _ko), (las3)(lds + _base + lo0), 16, 0, 0); \
      __builtin_amdgcn_global_load_lds((gas1)(ROW1 + _ko), (las3)(lds + _base + lo1), 16, 0, 0); \
    } while (0)
#define STAGE_A(KK, TT, BB) STAGE(arow0, arow1, 0u, KK, TT, BB)
#define STAGE_B(KK, TT, BB) STAGE(brow0, brow1, 65536u, KK, TT, BB)

#define LOAD_A4(DST, QM, KK, BB) do {                                                \
      _Pragma("unroll")                                                              \
      for (int i = 0; i < 4; ++i)                                                    \
        DST[i] = *(const bf16x8*)(lds + ((BB) * 32768u + (KK) * 16384u)              \
                                  + offA[(QM) * 4 + i]);                             \
    } while (0)

#define LOAD_B4(DST, KK, BB) do {                                                    \
      _Pragma("unroll")                                                              \
      for (int n = 0; n < 4; ++n)                                                    \
        DST[n] = *(const bf16x8*)(lds + ((BB) * 32768u + (KK) * 16384u) + offB[n]);  \
    } while (0)

#define MFMA16(QM, AF, BG) do {                                                      \
      _Pragma("unroll")                                                              \
      for (int i = 0; i < 4; ++i)                                                    \
        _Pragma("unroll")                                                            \
        for (int n = 0; n < 4; ++n)                                                  \
          acc[(QM) * 4 + i][n] = __builtin_amdgcn_mfma_f32_16x16x32_bf16(            \
              AF[i], BG[n], acc[(QM) * 4 + i][n], 0, 0, 0);                          \
    } while (0)

// One K-tile = 4 phases, ONE barrier each (closing). Stage/vmcnt placement
// identical to R3..R10. Reads for ph2-4 issue under the prior phase's MFMA.
#define KTILE(U, BB) do {                                                            \
      const int tt1 = ((U) + 1 < NTILE) ? (U) + 1 : (U) - 1;                         \
      const int tt2 = ((U) + 2 < NTILE) ? (U) + 2 : (U);                             \
      /* phase 1: kk=0 qm=0 (reads exposed: post-publication) */                     \
      LOAD_B4(bgA, 0, BB); LOAD_A4(af0, 0, 0, BB);                                   \
      STAGE_A(1, tt1, 1 - (BB));                                                     \
      __builtin_amdgcn_s_setprio(1); MFMA16(0, af0, bgA);                            \
      __builtin_amdgcn_s_setprio(0);                                                 \
      LOAD_A4(af1, 1, 0, BB);                                                        \
      BAR(); SCHEDB();                                                               \
      /* phase 2: kk=0 qm=1 */                                                       \
      STAGE_B(0, tt2, BB);                                                           \
      __builtin_amdgcn_s_setprio(1); MFMA16(1, af1, bgA);                            \
      __builtin_amdgcn_s_setprio(0);                                                 \
      LOAD_B4(bgB, 1, BB); LOAD_A4(af0, 0, 1, BB);                                   \
      BAR(); SCHEDB();                                                               \
      /* phase 3: kk=1 qm=0 */                                                       \
      STAGE_A(0, tt2, BB);                                                           \
      __builtin_amdgcn_s_setprio(1); MFMA16(0, af0, bgB);                            \
      __builtin_amdgcn_s_setprio(0);                                                 \
      LOAD_A4(af1, 1, 1, BB);                                                        \
      BAR(); SCHEDB();                                                               \
      /* phase 4: kk=1 qm=1 */                                                       \
      STAGE_B(1, tt2, BB);                                                           \
      __builtin_amdgcn_s_setprio(1); MFMA16(1, af1, bgB);                            \
      __builtin_amdgcn_s_setprio(0);                                                 \
      WAITVM6(); SCHEDB(); BAR(); SCHEDB();                                          \
    } while (0)

    f32x4 acc[8][4];
    #pragma unroll
    for (int i = 0; i < 8; ++i)
        #pragma unroll
        for (int j = 0; j < 4; ++j)
            acc[i][j] = (f32x4)0.0f;
    bf16x8 af0[4], af1[4], bgA[4], bgB[4];

    // Prologue: tile0 {Ak0,Bk0,Ak1,Bk1}, tile1 {Ak0,Bk0,Bk1}; 14 issued,
    // need first 8 (all of tile 0) -> vmcnt(6).
    STAGE_A(0, 0, 0); STAGE_B(0, 0, 0); STAGE_A(1, 0, 0); STAGE_B(1, 0, 0);
    STAGE_A(0, 1, 1); STAGE_B(0, 1, 1); STAGE_B(1, 1, 1);
    WAITVM6(); SCHEDB();
    BAR(); SCHEDB();

    #pragma unroll 1
    for (int u = 0; u < NTILE; u += 2) {
        KTILE(u, 0);
        KTILE(u + 1, 1);
    }
    WAITVM0();   // drain idempotent tail reloads before LDS dealloc

    // Epilogue: C/D layout col=lane&15, row=(lane>>4)*4+reg
    #pragma unroll
    for (int j = 0; j < 4; ++j) {
        int n = n0 + wc * 64 + j * 16 + l15;
        float bv = bias[n];
        #pragma unroll
        for (int i = 0; i < 8; ++i) {
            int mb = m0 + wr * 128 + i * 16 + (q4 << 2);
            #pragma unroll
            for (int r = 0; r < 4; ++r)
                C[(size_t)(mb + r) * N_TOT + n] = acc[i][j][r] + bv;
        }
    }
}

extern "C" void kernel_launch(void* const* d_in, const int* in_sizes, int n_in,
                              void* d_out, int out_size, void* d_ws, size_t ws_size,
                              hipStream_t stream) {
    const float* x    = (const float*)d_in[0];
    const float* w    = (const float*)d_in[1];
    const float* bias = (const float*)d_in[2];
    float* out = (float*)d_out;

    unsigned short* wb = (unsigned short*)d_ws;                      // 32 MiB
    unsigned short* xb = wb + (size_t)N_TOT * K_TOT;                 // +64 MiB

    prep_kernel<<<4096, 256, 0, stream>>>(w, wb, x, xb);

    hipFuncSetAttribute(reinterpret_cast<const void*>(gemm_kernel),
                        hipFuncAttributeMaxDynamicSharedMemorySize, 131072);
    gemm_kernel<<<512, 512, 131072, stream>>>(xb, wb, bias, out);
}